// Round 8
// baseline (134.686 us; speedup 1.0000x reference)
//
#include <hip/hip_runtime.h>
#include <hip/hip_bf16.h>
#include <stdint.h>

// ContrastiveLoss: N=8192, D=512 fp32 features, int labels {0,1}.
// out = mean_i [ (np_i * log(sum_exp_i) - sum_pos_i) / (np_i + 1e-8) ]
// R1: global_load_lds(16B) + XOR-swizzled LDS (conflict-free b128 reads).
// R2: upper-triangle tiles only (2080). R3: collision-free partial slots.
// R5: fp8-e4m3 (x16 pre-scale; k pre-permuted identically for A/B).
// R7: XCD swizzle (FETCH 71->15 MB) + register-only epilogue.
// R8: occupancy attack: 512-thread blocks, 8 waves of 32x64 (acc 32 VGPR,
//     ~80 total vs 128) -> launch_bounds(512,6): 6 waves/SIMD, 3 blocks/CU.
//     Cols now 4 partials (wm) -> LDS ds_add fold into 2 groups -> slot
//     2bi+g. Coverage: slot 2b+h region r: r<=b row-writer (r,b) wn=h;
//     r>b col-writer (b,r) g=h; exactly once each.

#define N_ROWS 8192
#define DIMF 512
#define DIMB 512
#define BKB 128
#define NB 64
#define NSLOT 128
#define SIM_SCALE 0.0390625f  // 10 / 256  (features pre-scaled by 16)

typedef float f32x4 __attribute__((ext_vector_type(4)));
typedef int64_t i64x2 __attribute__((ext_vector_type(2)));

__device__ static inline void gload_lds16(const uint8_t* g, uint8_t* l) {
    __builtin_amdgcn_global_load_lds(
        (const __attribute__((address_space(1))) unsigned int*)g,
        (__attribute__((address_space(3))) unsigned int*)l, 16, 0, 0);
}

// 4 waves/block, one row per wave: fp32 sumsq -> scale by 16/norm -> fp8,
// stored k-permuted per 128B tile: (ks,q) -> q*32+ks*8 (dot-invariant).
// Block 0 also counts label-1s and zeroes out[0].
__global__ __launch_bounds__(256) void norm_kernel(const float* __restrict__ x,
                                                   uint8_t* __restrict__ f8,
                                                   const int* __restrict__ lab,
                                                   int* __restrict__ cnt,
                                                   float* __restrict__ out) {
    __shared__ int shc[4];
    const int wave = threadIdx.x >> 6, t = threadIdx.x & 63;
    const int row = blockIdx.x * 4 + wave;
    const float4* xr = (const float4*)(x + (size_t)row * DIMF);
    float4 v0 = xr[2 * t];
    float4 v1 = xr[2 * t + 1];
    float ss = v0.x * v0.x + v0.y * v0.y + v0.z * v0.z + v0.w * v0.w +
               v1.x * v1.x + v1.y * v1.y + v1.z * v1.z + v1.w * v1.w;
#pragma unroll
    for (int off = 32; off >= 1; off >>= 1) ss += __shfl_xor(ss, off, 64);
    float s = 16.0f / fmaxf(sqrtf(ss), 1e-12f);
    int lo = 0, hi = 0;
    lo = __builtin_amdgcn_cvt_pk_fp8_f32(v0.x * s, v0.y * s, lo, false);
    lo = __builtin_amdgcn_cvt_pk_fp8_f32(v0.z * s, v0.w * s, lo, true);
    hi = __builtin_amdgcn_cvt_pk_fp8_f32(v1.x * s, v1.y * s, hi, false);
    hi = __builtin_amdgcn_cvt_pk_fp8_f32(v1.z * s, v1.w * s, hi, true);
    int2 pk;
    pk.x = lo;
    pk.y = hi;
    const int pos = (t >> 4) * 128 + (t & 3) * 32 + ((t >> 2) & 3) * 8;
    *(int2*)(f8 + (size_t)row * DIMB + pos) = pk;

    if (blockIdx.x == 0) {
        int local = 0;
        for (int i = threadIdx.x; i < N_ROWS; i += 256) local += lab[i];
#pragma unroll
        for (int off = 32; off >= 1; off >>= 1) local += __shfl_xor(local, off, 64);
        if (t == 0) shc[wave] = local;
        __syncthreads();
        if (threadIdx.x == 0) {
            cnt[0] = shc[0] + shc[1] + shc[2] + shc[3];
            out[0] = 0.0f;
        }
    }
}

// 128x128 tile/block; 8 waves (4x2), each 32x64 via 2x4 MFMA 16x16x32 fp8.
// BK=128B via global_load_lds(16B) into XOR-swizzled LDS rows of 128B:
// phys 16B-unit = logical ^ (row&7). Waves 0-3 stage sA, 4-7 stage sB.
__global__ __launch_bounds__(512, 6) void sim_kernel(const uint8_t* __restrict__ f8,
                                                     const int* __restrict__ lab,
                                                     float* __restrict__ PE,
                                                     float* __restrict__ PP) {
    __shared__ __align__(16) uint8_t smem[32768];
    uint8_t* sA = smem;
    uint8_t* sB = smem + 16384;
    float* colbuf = (float*)smem;  // 512 floats, aliased after K-loop

    // XCD-locality swizzle (2080 = 8 * 260); decode upper-triangle index.
    const int tblk = (blockIdx.x & 7) * 260 + (blockIdx.x >> 3);
    int bi = (int)(64.5f - sqrtf(64.5f * 64.5f - 2.0f * (float)tblk));
    while (bi * (129 - bi) / 2 > tblk) --bi;
    while ((bi + 1) * (128 - bi) / 2 <= tblk) ++bi;
    const int bj = bi + (tblk - bi * (129 - bi) / 2);
    const bool diag = (bi == bj);

    const int t = threadIdx.x;
    const int iBase = bi * 128, jBase = bj * 128;
    const int lane = t & 63, wave = t >> 6;
    const int wm = wave >> 1, wn = wave & 1;  // wm in [0,4): 32-row strip; wn in [0,2): 64-col half
    const int lrow = lane & 15, quad = lane >> 4;

    // staging role: waves 0-3 -> sA rows (wave&3)*32.. ; waves 4-7 -> sB
    const int sub = lane >> 3;        // row within 8-row chunk
    const int lu = (lane & 7) ^ sub;  // swizzled 16B source unit
    const bool stA = wave < 4;
    const int wr = (wave & 3) * 32;
    const uint8_t* gbase =
        f8 + (size_t)((stA ? iBase : jBase) + wr + sub) * DIMB + lu * 16;
    uint8_t* lbase = (stA ? sA : sB) + wr * 128;

    f32x4 acc[2][4] = {};

    for (int kk = 0; kk < DIMB; kk += BKB) {
#pragma unroll
        for (int c = 0; c < 4; ++c)
            gload_lds16(gbase + (size_t)(c * 8) * DIMB + kk, lbase + c * 8 * 128);
        __syncthreads();
#pragma unroll
        for (int p = 0; p < 2; ++p) {
            const int su = (((quad << 1) + p) ^ (lrow & 7)) << 4;
            i64x2 af[2], bfr[4];
#pragma unroll
            for (int m = 0; m < 2; ++m)
                af[m] = *(const i64x2*)(sA + (wm * 32 + m * 16 + lrow) * 128 + su);
#pragma unroll
            for (int n = 0; n < 4; ++n)
                bfr[n] = *(const i64x2*)(sB + (wn * 64 + n * 16 + lrow) * 128 + su);
#pragma unroll
            for (int m = 0; m < 2; ++m)
#pragma unroll
                for (int n = 0; n < 4; ++n) {
                    acc[m][n] = __builtin_amdgcn_mfma_f32_16x16x32_fp8_fp8(
                        af[m].x, bfr[n].x, acc[m][n], 0, 0, 0);
                    acc[m][n] = __builtin_amdgcn_mfma_f32_16x16x32_fp8_fp8(
                        af[m].y, bfr[n].y, acc[m][n], 0, 0, 0);
                }
        }
        __syncthreads();
    }

    // sA/sB free; colbuf layout: E at [g*128+c], P at [256 + g*128+c].
    colbuf[t] = 0.0f;
    __syncthreads();

    // Epilogue. C/D layout: col = lane&15, row = quad*4 + reg (m89-verified).
    int labj[4];
#pragma unroll
    for (int n = 0; n < 4; ++n) labj[n] = lab[jBase + wn * 64 + n * 16 + lrow];

    const int slotR = 2 * bj + wn;
    float sec[4] = {0, 0, 0, 0}, spc[4] = {0, 0, 0, 0};

#pragma unroll
    for (int m = 0; m < 2; ++m) {
        const int4 labi4 = *(const int4*)&lab[iBase + wm * 32 + m * 16 + quad * 4];
        float rE[4], rP[4];
#pragma unroll
        for (int e = 0; e < 4; ++e) {
            const int r = wm * 32 + m * 16 + quad * 4 + e;
            const int i = iBase + r;
            const int labi = (&labi4.x)[e];
            float se = 0.0f, sp = 0.0f;
            if (diag) {
#pragma unroll
                for (int n = 0; n < 4; ++n) {
                    const int j = jBase + wn * 64 + n * 16 + lrow;
                    const float sim = acc[m][n][e] * SIM_SCALE;
                    if (j != i) {
                        se += __expf(sim);
                        if (labj[n] == labi) sp += sim;
                    }
                }
            } else {
#pragma unroll
                for (int n = 0; n < 4; ++n) {
                    const float sim = acc[m][n][e] * SIM_SCALE;
                    const float ex = __expf(sim);
                    se += ex;
                    sec[n] += ex;
                    if (labj[n] == labi) {
                        sp += sim;
                        spc[n] += sim;
                    }
                }
            }
#pragma unroll
            for (int off = 8; off >= 1; off >>= 1) {
                se += __shfl_xor(se, off, 16);
                sp += __shfl_xor(sp, off, 16);
            }
            rE[e] = se;
            rP[e] = sp;
        }
        if (lrow == 0) {
            const size_t o =
                (size_t)slotR * N_ROWS + iBase + wm * 32 + m * 16 + quad * 4;
            float4 vE = {rE[0], rE[1], rE[2], rE[3]};
            float4 vP = {rP[0], rP[1], rP[2], rP[3]};
            *(float4*)&PE[o] = vE;
            *(float4*)&PP[o] = vP;
        }
    }

    if (!diag) {
        // fold quads in-wave, then wm-pairs (g = wm>>1) via LDS ds_add.
#pragma unroll
        for (int n = 0; n < 4; ++n) {
            sec[n] += __shfl_xor(sec[n], 16, 64);
            sec[n] += __shfl_xor(sec[n], 32, 64);
            spc[n] += __shfl_xor(spc[n], 16, 64);
            spc[n] += __shfl_xor(spc[n], 32, 64);
        }
        if (quad == 0) {
            const int g = wm >> 1;
#pragma unroll
            for (int n = 0; n < 4; ++n) {
                const int c = wn * 64 + n * 16 + lrow;
                atomicAdd(&colbuf[g * 128 + c], sec[n]);
                atomicAdd(&colbuf[256 + g * 128 + c], spc[n]);
            }
        }
    }
    __syncthreads();

    if (!diag && t < 256) {
        const int g = t >> 7, c = t & 127;
        const size_t o = (size_t)(2 * bi + g) * N_ROWS + jBase + c;
        PE[o] = colbuf[g * 128 + c];
        PP[o] = colbuf[256 + g * 128 + c];
    }
}

// 32 blocks x 256 rows: sum 128 slots, per-row loss, atomicAdd mean into out.
__global__ __launch_bounds__(256) void final_kernel(const float* __restrict__ PE,
                                                    const float* __restrict__ PP,
                                                    const int* __restrict__ lab,
                                                    const int* __restrict__ cnt,
                                                    float* __restrict__ out) {
    const int i = blockIdx.x * 256 + threadIdx.x;
    float se = 0.0f, sp = 0.0f;
#pragma unroll 8
    for (int s = 0; s < NSLOT; ++s) {
        se += PE[(size_t)s * N_ROWS + i];
        sp += PP[(size_t)s * N_ROWS + i];
    }
    const float c1 = (float)cnt[0];
    float np = (lab[i] ? c1 : (float)N_ROWS - c1) - 1.0f;
    float local = (np * __logf(se) - sp) / (np + 1e-8f);
    __shared__ float sh[4];
    int lane = threadIdx.x & 63, w = threadIdx.x >> 6;
#pragma unroll
    for (int off = 32; off >= 1; off >>= 1) local += __shfl_xor(local, off, 64);
    if (lane == 0) sh[w] = local;
    __syncthreads();
    if (threadIdx.x == 0)
        atomicAdd(out, (sh[0] + sh[1] + sh[2] + sh[3]) * (1.0f / (float)N_ROWS));
}

extern "C" void kernel_launch(void* const* d_in, const int* in_sizes, int n_in,
                              void* d_out, int out_size, void* d_ws, size_t ws_size,
                              hipStream_t stream) {
    const float* features = (const float*)d_in[0];
    const int* labels = (const int*)d_in[1];
    float* out = (float*)d_out;

    char* ws = (char*)d_ws;
    uint8_t* f8 = (uint8_t*)ws;                              // 4 MiB
    float* PE = (float*)(ws + (size_t)N_ROWS * DIMB);        // 4 MiB
    float* PP = PE + (size_t)NSLOT * N_ROWS;                 // 4 MiB
    int* cnt = (int*)(PP + (size_t)NSLOT * N_ROWS);          // 4 B

    norm_kernel<<<N_ROWS / 4, 256, 0, stream>>>(features, f8, labels, cnt, out);
    sim_kernel<<<NB * (NB + 1) / 2, 512, 0, stream>>>(f8, labels, PE, PP);
    final_kernel<<<N_ROWS / 256, 256, 0, stream>>>(PE, PP, labels, cnt, out);
}

// Round 9
// 120.994 us; speedup vs baseline: 1.1132x; 1.1132x over previous
//
#include <hip/hip_runtime.h>
#include <hip/hip_bf16.h>
#include <stdint.h>

// ContrastiveLoss: N=8192, D=512 fp32 features, int labels {0,1}.
// out = mean_i [ (np_i * log(sum_exp_i) - sum_pos_i) / (np_i + 1e-8) ]
// R1: global_load_lds(16B) + XOR-swizzled LDS (bank-floor b128 reads).
// R2: upper-triangle tiles (2080). R3: collision-free partial slots.
// R5: fp8-e4m3 (x16 pre-scale; k pre-permuted identically for A/B).
// R7: XCD swizzle (FETCH 71->15 MB) + register-only epilogue. 54.5 us.
// R8 post-mortem: occupancy 34->49% changed nothing -> limiter is the
//     per-K-iter vmcnt(0) barrier drain (zero compute coverage).
// R9: pipelined K-loop, BK=64, LDS dbuf (2x16 KB, still 4 blocks/CU):
//     batch kk+1 issued AFTER barrier kk, BEFORE compute kk -> every
//     barrier drains a batch that is one full compute phase old (free);
//     only kk=0 stalls cold. Single barrier/iter (readers of the buffer
//     being overwritten finished before the preceding barrier).

#define N_ROWS 8192
#define DIMF 512
#define DIMB 512
#define NB 64
#define NSLOT 128
#define SIM_SCALE 0.0390625f  // 10 / 256  (features pre-scaled by 16)

typedef float f32x4 __attribute__((ext_vector_type(4)));
typedef int64_t i64x2 __attribute__((ext_vector_type(2)));

__device__ static inline void gload_lds16(const uint8_t* g, uint8_t* l) {
    __builtin_amdgcn_global_load_lds(
        (const __attribute__((address_space(1))) unsigned int*)g,
        (__attribute__((address_space(3))) unsigned int*)l, 16, 0, 0);
}

// 4 waves/block, one row per wave: fp32 sumsq -> scale by 16/norm -> fp8,
// k-permuted per 64B tile: orig (c,q) byte-group -> q*16 + c*8 (c=k5, q=k43).
// Identical permute on A and B leaves every dot product invariant.
// Block 0 thread 0 zeroes out[0] (d_out is poisoned each replay).
__global__ __launch_bounds__(256) void norm_kernel(const float* __restrict__ x,
                                                   uint8_t* __restrict__ f8,
                                                   float* __restrict__ out) {
    const int wave = threadIdx.x >> 6, t = threadIdx.x & 63;
    const int row = blockIdx.x * 4 + wave;
    const float4* xr = (const float4*)(x + (size_t)row * DIMF);
    float4 v0 = xr[2 * t];
    float4 v1 = xr[2 * t + 1];
    float ss = v0.x * v0.x + v0.y * v0.y + v0.z * v0.z + v0.w * v0.w +
               v1.x * v1.x + v1.y * v1.y + v1.z * v1.z + v1.w * v1.w;
#pragma unroll
    for (int off = 32; off >= 1; off >>= 1) ss += __shfl_xor(ss, off, 64);
    float s = 16.0f / fmaxf(sqrtf(ss), 1e-12f);
    int lo = 0, hi = 0;
    lo = __builtin_amdgcn_cvt_pk_fp8_f32(v0.x * s, v0.y * s, lo, false);
    lo = __builtin_amdgcn_cvt_pk_fp8_f32(v0.z * s, v0.w * s, lo, true);
    hi = __builtin_amdgcn_cvt_pk_fp8_f32(v1.x * s, v1.y * s, hi, false);
    hi = __builtin_amdgcn_cvt_pk_fp8_f32(v1.z * s, v1.w * s, hi, true);
    int2 pk;
    pk.x = lo;
    pk.y = hi;
    const int pos = (t >> 3) * 64 + (t & 3) * 16 + ((t >> 2) & 1) * 8;
    *(int2*)(f8 + (size_t)row * DIMB + pos) = pk;
    if (blockIdx.x == 0 && threadIdx.x == 0) out[0] = 0.0f;
}

// 128x128 tile/block (4 waves 2x2, each 64x64 via 4x4x(2p) MFMA 16x16x32
// fp8). BK=64B, double-buffered. LDS rows of 64B = 4 x 16B units; phys
// unit = logical ^ ((row>>1)&3) -> b128 frag reads at the bank floor.
__global__ __launch_bounds__(256, 4) void sim_kernel(const uint8_t* __restrict__ f8,
                                                     const int* __restrict__ lab,
                                                     float* __restrict__ PE,
                                                     float* __restrict__ PP) {
    __shared__ __align__(16) uint8_t sA[2][128 * 64];
    __shared__ __align__(16) uint8_t sB[2][128 * 64];

    // XCD-locality swizzle (2080 = 8 * 260); decode upper-triangle index.
    const int tblk = (blockIdx.x & 7) * 260 + (blockIdx.x >> 3);
    int bi = (int)(64.5f - sqrtf(64.5f * 64.5f - 2.0f * (float)tblk));
    while (bi * (129 - bi) / 2 > tblk) --bi;
    while ((bi + 1) * (128 - bi) / 2 <= tblk) ++bi;
    const int bj = bi + (tblk - bi * (129 - bi) / 2);
    const bool diag = (bi == bj);

    const int t = threadIdx.x;
    const int iBase = bi * 128, jBase = bj * 128;
    const int lane = t & 63, wave = t >> 6;
    const int wm = wave >> 1, wn = wave & 1;
    const int lrow = lane & 15, quad = lane >> 4;

    // staging: each instr covers 16 rows x 4 phys units (1 KB). lane ->
    // row sub, phys unit lane&3, source logical unit (lane&3)^((sub>>1)&3).
    const int sub = lane >> 2;
    const int lu = (lane & 3) ^ ((sub >> 1) & 3);
    // wave strip: rows wave*32 + c*16 + sub, c in {0,1}
    const size_t gA0 = (size_t)(iBase + wave * 32 + sub) * DIMB + lu * 16;
    const size_t gB0 = (size_t)(jBase + wave * 32 + sub) * DIMB + lu * 16;

    f32x4 acc[4][4] = {};

    // prologue: stage batch 0 into buffer 0
#pragma unroll
    for (int c = 0; c < 2; ++c) {
        gload_lds16(f8 + gA0 + (size_t)(c * 16) * DIMB, sA[0] + (wave * 32 + c * 16) * 64);
        gload_lds16(f8 + gB0 + (size_t)(c * 16) * DIMB, sB[0] + (wave * 32 + c * 16) * 64);
    }

#pragma unroll
    for (int kk = 0; kk < 8; ++kk) {
        const int cur = kk & 1;
        __syncthreads();  // drains batch kk: one full compute phase old (kk>0)
        if (kk < 7) {
#pragma unroll
            for (int c = 0; c < 2; ++c) {
                gload_lds16(f8 + gA0 + (size_t)(c * 16) * DIMB + (kk + 1) * 64,
                            sA[cur ^ 1] + (wave * 32 + c * 16) * 64);
                gload_lds16(f8 + gB0 + (size_t)(c * 16) * DIMB + (kk + 1) * 64,
                            sB[cur ^ 1] + (wave * 32 + c * 16) * 64);
            }
        }
        // compute on buffer cur while batch kk+1 flies
        const int pu = (quad ^ ((lrow >> 1) & 3)) * 16;
        i64x2 af[4], bfr[4];
#pragma unroll
        for (int m = 0; m < 4; ++m)
            af[m] = *(const i64x2*)(sA[cur] + (wm * 64 + m * 16 + lrow) * 64 + pu);
#pragma unroll
        for (int n = 0; n < 4; ++n)
            bfr[n] = *(const i64x2*)(sB[cur] + (wn * 64 + n * 16 + lrow) * 64 + pu);
#pragma unroll
        for (int m = 0; m < 4; ++m)
#pragma unroll
            for (int n = 0; n < 4; ++n) {
                acc[m][n] = __builtin_amdgcn_mfma_f32_16x16x32_fp8_fp8(
                    af[m].x, bfr[n].x, acc[m][n], 0, 0, 0);
                acc[m][n] = __builtin_amdgcn_mfma_f32_16x16x32_fp8_fp8(
                    af[m].y, bfr[n].y, acc[m][n], 0, 0, 0);
            }
    }

    // Register-only epilogue. C/D layout: col=lane&15, row=quad*4+reg.
    int labj[4];
#pragma unroll
    for (int n = 0; n < 4; ++n) labj[n] = lab[jBase + wn * 64 + n * 16 + lrow];

    const int slotR = 2 * bj + wn;  // rows of iBase
    const int slotC = 2 * bi + wm;  // cols of jBase
    float sec[4] = {0, 0, 0, 0}, spc[4] = {0, 0, 0, 0};

#pragma unroll
    for (int m = 0; m < 4; ++m) {
        float rE[4], rP[4];
#pragma unroll
        for (int e = 0; e < 4; ++e) {
            const int r = wm * 64 + m * 16 + quad * 4 + e;
            const int i = iBase + r;
            const int labi = lab[i];
            float se = 0.0f, sp = 0.0f;
            if (diag) {
#pragma unroll
                for (int n = 0; n < 4; ++n) {
                    const int j = jBase + wn * 64 + n * 16 + lrow;
                    const float sim = acc[m][n][e] * SIM_SCALE;
                    if (j != i) {
                        se += __expf(sim);
                        if (labj[n] == labi) sp += sim;
                    }
                }
            } else {
#pragma unroll
                for (int n = 0; n < 4; ++n) {
                    const float sim = acc[m][n][e] * SIM_SCALE;
                    const float ex = __expf(sim);
                    se += ex;
                    sec[n] += ex;
                    if (labj[n] == labi) {
                        sp += sim;
                        spc[n] += sim;
                    }
                }
            }
#pragma unroll
            for (int off = 8; off >= 1; off >>= 1) {
                se += __shfl_xor(se, off, 16);
                sp += __shfl_xor(sp, off, 16);
            }
            rE[e] = se;
            rP[e] = sp;
        }
        if (lrow == 0) {
            const size_t o = (size_t)slotR * N_ROWS + iBase + wm * 64 + m * 16 + quad * 4;
            float4 vE = {rE[0], rE[1], rE[2], rE[3]};
            float4 vP = {rP[0], rP[1], rP[2], rP[3]};
            *(float4*)&PE[o] = vE;
            *(float4*)&PP[o] = vP;
        }
    }

    if (!diag) {
#pragma unroll
        for (int n = 0; n < 4; ++n) {
            sec[n] += __shfl_xor(sec[n], 16, 64);
            sec[n] += __shfl_xor(sec[n], 32, 64);
            spc[n] += __shfl_xor(spc[n], 16, 64);
            spc[n] += __shfl_xor(spc[n], 32, 64);
        }
        if (quad == 0) {
#pragma unroll
            for (int n = 0; n < 4; ++n) {
                const size_t o = (size_t)slotC * N_ROWS + jBase + wn * 64 + n * 16 + lrow;
                PE[o] = sec[n];
                PP[o] = spc[n];
            }
        }
    }
}

// 32 blocks x 256 rows: per-block label count (no serial tail, no cnt buf),
// sum 128 slots, per-row loss, atomicAdd mean into out.
__global__ __launch_bounds__(256) void final_kernel(const float* __restrict__ PE,
                                                    const float* __restrict__ PP,
                                                    const int* __restrict__ lab,
                                                    float* __restrict__ out) {
    __shared__ float shc;
    __shared__ float sh[4];
    int cl = 0;
#pragma unroll 4
    for (int s = threadIdx.x; s < N_ROWS; s += 256) cl += lab[s];
#pragma unroll
    for (int off = 32; off >= 1; off >>= 1) cl += __shfl_xor(cl, off, 64);
    const int lane = threadIdx.x & 63, w = threadIdx.x >> 6;
    if (lane == 0) sh[w] = (float)cl;
    __syncthreads();
    if (threadIdx.x == 0) shc = sh[0] + sh[1] + sh[2] + sh[3];
    __syncthreads();
    const float c1 = shc;

    const int i = blockIdx.x * 256 + threadIdx.x;
    float se = 0.0f, sp = 0.0f;
#pragma unroll 8
    for (int s = 0; s < NSLOT; ++s) {
        se += PE[(size_t)s * N_ROWS + i];
        sp += PP[(size_t)s * N_ROWS + i];
    }
    float np = (lab[i] ? c1 : (float)N_ROWS - c1) - 1.0f;
    float local = (np * __logf(se) - sp) / (np + 1e-8f);
#pragma unroll
    for (int off = 32; off >= 1; off >>= 1) local += __shfl_xor(local, off, 64);
    __syncthreads();
    if (lane == 0) sh[w] = local;
    __syncthreads();
    if (threadIdx.x == 0)
        atomicAdd(out, (sh[0] + sh[1] + sh[2] + sh[3]) * (1.0f / (float)N_ROWS));
}

extern "C" void kernel_launch(void* const* d_in, const int* in_sizes, int n_in,
                              void* d_out, int out_size, void* d_ws, size_t ws_size,
                              hipStream_t stream) {
    const float* features = (const float*)d_in[0];
    const int* labels = (const int*)d_in[1];
    float* out = (float*)d_out;

    char* ws = (char*)d_ws;
    uint8_t* f8 = (uint8_t*)ws;                              // 4 MiB
    float* PE = (float*)(ws + (size_t)N_ROWS * DIMB);        // 4 MiB
    float* PP = PE + (size_t)NSLOT * N_ROWS;                 // 4 MiB

    norm_kernel<<<N_ROWS / 4, 256, 0, stream>>>(features, f8, out);
    sim_kernel<<<NB * (NB + 1) / 2, 256, 0, stream>>>(f8, labels, PE, PP);
    final_kernel<<<N_ROWS / 256, 256, 0, stream>>>(PE, PP, labels, out);
}